// Round 12
// baseline (201.226 us; speedup 1.0000x reference)
//
#include <hip/hip_runtime.h>
#include <hip/hip_bf16.h>
#include <math.h>

#define D_MODEL 1024
#define N_HEADS 16
#define D_K 64
#define N_CLASSES 32
#define S_LEN 16
#define BATCH 32
#define T_LEN 512

typedef __bf16 bf16_t;
typedef bf16_t bf16x8 __attribute__((ext_vector_type(8)));
typedef float f32x4 __attribute__((ext_vector_type(4)));
typedef long lx2 __attribute__((ext_vector_type(2)));

__device__ inline unsigned short f2bf(float f) {
    unsigned int u = __float_as_uint(f);
    unsigned int r = (u + 0x7FFFu + ((u >> 16) & 1u)) >> 16;   // RNE
    return (unsigned short)r;
}
// fast tanh: (e-1)/(e+1), e = exp(2x). Valid for |x| < 40. rel err ~1e-6.
__device__ inline float fast_tanh(float x) {
    float e = __expf(2.0f * x);
    return (e - 1.0f) * __builtin_amdgcn_rcpf(e + 1.0f);
}
__device__ inline float4 fast_tanh4(float4 v) {
    return make_float4(fast_tanh(v.x), fast_tanh(v.y), fast_tanh(v.z), fast_tanh(v.w));
}
__device__ inline float dot4(float4 a, float4 b) {
    return a.x * b.x + a.y * b.y + a.z * b.z + a.w * b.w;
}
// bare v_exp_f32: D = 2^x (scores pre-scaled by log2e via Q)
__device__ inline float exp2_fast(float x) {
    float r;
    asm("v_exp_f32 %0, %1" : "=v"(r) : "v"(x));
    return r;
}
// pack 4 floats -> 4 e4m3 bytes (OCP, HW cvt)
__device__ inline int pack_fp8x4(float4 v) {
    int p = __builtin_amdgcn_cvt_pk_fp8_f32(v.x, v.y, 0, false);
    p = __builtin_amdgcn_cvt_pk_fp8_f32(v.z, v.w, p, true);
    return p;
}
// 8 consecutive f32 -> bf16x8 fragment
__device__ inline bf16x8 bf8_from_f32(const float* p) {
    float4 a = *(const float4*)p;
    float4 b = *(const float4*)(p + 4);
    union { bf16x8 v; unsigned short s[8]; } u;
    u.s[0] = f2bf(a.x); u.s[1] = f2bf(a.y); u.s[2] = f2bf(a.z); u.s[3] = f2bf(a.w);
    u.s[4] = f2bf(b.x); u.s[5] = f2bf(b.y); u.s[6] = f2bf(b.z); u.s[7] = f2bf(b.w);
    return u.v;
}

// async global->LDS, 16 bytes per lane (global_load_lds_dwordx4)
__device__ inline void async16(void* lds, const void* g) {
    __builtin_amdgcn_global_load_lds(
        (const __attribute__((address_space(1))) unsigned int*)g,
        (__attribute__((address_space(3))) unsigned int*)lds, 16, 0, 0);
}

// ================= prep: wql-splitK ∥ fp8-swizzle cvt ∥ bf16 cvt ============
// ROUND-8-VERIFIED. wql must stay WIDE (256 split-K blocks + atomics) --
// twice-confirmed lesson (rounds 3 & 9): narrow wql rewrites create a serial
// tail; the memset is noise, the parallelism is not.
__global__ __launch_bounds__(256) void prep_kernel(
    const float* __restrict__ H, int* __restrict__ Hf8,
    const float* __restrict__ WK, int* __restrict__ WKf8,
    const float4* __restrict__ Q, ushort4* __restrict__ Qb,
    const float4* __restrict__ WQ, ushort4* __restrict__ WQb,
    const float* __restrict__ ql, const float* __restrict__ WV,
    float* __restrict__ wql)
{
    __shared__ __align__(16) char psm[25600];
    const int bid = blockIdx.x;
    const int tid = threadIdx.x;
    if (bid < 256) {
        // ---- wql split-K: wql[c][n] += sum_{k0..k0+63} ql[c][k]*WV[n][k] ----
        float4 (*qls)[16] = (float4(*)[16])psm;               // [32][16]  8 KB
        float4 (*WVs)[17] = (float4(*)[17])(psm + 8192);      // [64][17] 17.4 KB
        const int n0 = (bid & 15) * 64;
        const int k0 = (bid >> 4) * 64;
        for (int i = tid; i < 512; i += 256)
            qls[i >> 4][i & 15] = *(const float4*)(ql + (size_t)(i >> 4) * D_MODEL + k0 + (i & 15) * 4);
        for (int i = tid; i < 1024; i += 256)
            WVs[i >> 4][i & 15] = *(const float4*)(WV + (size_t)(n0 + (i >> 4)) * D_MODEL + k0 + (i & 15) * 4);
        __syncthreads();

        const int n = tid & 63;
        const int c0 = (tid >> 6) * 8;
        float acc[8] = {};
        for (int kq = 0; kq < 16; kq++) {
            const float4 wv = WVs[n][kq];
#pragma unroll
            for (int c = 0; c < 8; c++) acc[c] += dot4(qls[c0 + c][kq], wv);
        }
#pragma unroll
        for (int c = 0; c < 8; c++)
            atomicAdd(&wql[(size_t)(c0 + c) * D_MODEL + n0 + n], acc[c]);
    } else if (bid < 4608) {
        // ---- LDS-mediated fp8 swizzle cvt: H (4096 CTAs), WK (256 CTAs) ----
        float (*L)[260] = (float(*)[260])psm;   // 16 x 260 floats = 16.6 KB
        int j = bid - 256;
        const float* in; int* out; float s; int jj;
        if (j < 4096) { in = H; out = Hf8; s = 1.0f; jj = j; }
        else { in = WK; out = WKf8; s = 512.0f; jj = j - 4096; }
        const int rb = jj >> 2;
        const int kb0 = (jj & 3) * 4;
        const float* base = in + (size_t)rb * 16 * 1024 + kb0 * 64;
#pragma unroll
        for (int it = 0; it < 4; it++) {
            const int idx = it * 256 + tid;
            const int row = idx >> 6;            // 0..15
            const int c0 = (idx & 63) * 4;       // 0..252
            *(float4*)&L[row][c0] = *(const float4*)(base + (size_t)row * 1024 + c0);
        }
        __syncthreads();
        const int quad = tid >> 6;
        const int l16 = (tid >> 2) & 15;
        const int kh = (tid & 3) >> 1;
        const int b0 = (tid & 1) * 4;
        const int klb = kh * 32 + quad * 8 + b0;
        int* outp = out + (size_t)jj * 1024 + tid;
#pragma unroll
        for (int p = 0; p < 4; p++) {
            float4 v = *(const float4*)&L[l16][p * 64 + klb];
            v.x *= s; v.y *= s; v.z *= s; v.w *= s;
            outp[p * 256] = pack_fp8x4(v);
        }
    } else {
        // ---- bf16 cvt: Q (131072 float4, x log2e), WQ (262144 float4) ------
        int i = (bid - 4608) * 256 + tid;
        const float4* in; ushort4* out; float s;
        if (i < 131072) { in = Q + i; out = Qb + i; s = 1.4426950408889634f; }
        else { i -= 131072; in = WQ + i; out = WQb + i; s = 1.0f; }
        float4 v = *in;
        ushort4 o;
        o.x = f2bf(v.x * s); o.y = f2bf(v.y * s); o.z = f2bf(v.z * s); o.w = f2bf(v.w * s);
        *out = o;
    }
}

// ================= gemms: fp8 GEMM ∥ qproj bf16 GEMM ∥ kv GEMM ==============
// THIS ROUND: role-MIXED dispatch. Old map was role-phased (fp8 blocks 0-1023
// = exactly the machine's 4-blocks/CU capacity -> a pure-MFMA phase, then a
// pure-memory kv phase; pipes serialize). New map: qproj's 32 long blocks
// FIRST (no tail), then a 1:2 interleave of fp8:kv (exact block-count ratio)
// so each CU co-hosts MFMA-heavy and memory/VALU-heavy blocks -- m114: MFMA
// and VALU/mem waves co-schedule at max-not-sum. Role bodies unchanged.
__global__ __launch_bounds__(256) void gemms_kernel(
    const unsigned char* __restrict__ A8, const unsigned char* __restrict__ B8,
    unsigned short* __restrict__ wkt_b,
    const unsigned short* __restrict__ Qb, const unsigned short* __restrict__ WQb,
    unsigned short* __restrict__ qproj_b,
    const float* __restrict__ H, const float* __restrict__ wql,
    float* __restrict__ kv)
{
    __shared__ __align__(16) char smem[33280];
    const int bid = blockIdx.x;
    const int tid = threadIdx.x;
    const int wid = tid >> 6;
    const int lane = tid & 63;
    const int quad = lane >> 4;
    const int l16 = lane & 15;

    // role decode: 32 qproj first, then interleaved {1 fp8, 2 kv} x 1024
    int role, rb_;
    if (bid < 32) { role = 1; rb_ = bid; }
    else {
        const int j = bid - 32;
        const int r = j % 3;
        if (r == 0) { role = 0; rb_ = j / 3; }          // fp8: 0..1023
        else        { role = 2; rb_ = (j / 3) * 2 + (r - 1); }  // kv: 0..2047
    }

    if (role == 0) {
        // ---- fp8 GEMM: wkt = bf16(fast_tanh((H8 @ WK8^T)/512)), 16384x1024 ---
        unsigned char* As = (unsigned char*)smem;           // 2 x 8 KB
        unsigned char* Bs = (unsigned char*)smem + 16384;   // 2 x 8 KB
        const int m0 = (rb_ & 127) * 128;   // m-fast grid (round-8-verified)
        const int n0 = (rb_ >> 7) * 128;
        const int wm = (wid >> 1) * 64;
        const int wn = (wid & 1) * 64;
        const int stA = wm >> 4;
        const int stB = wn >> 4;
        const int st = wid;
        const int cl = lane * 16;

        f32x4 acc[4][4] = {};
        const unsigned char* Ab = A8 + ((size_t)(m0 >> 4) * 16) * 1024;
        const unsigned char* Bb = B8 + ((size_t)(n0 >> 4) * 16) * 1024;

        auto stage = [&](int buf, int kb) {
            async16(&As[buf * 8192 + tid * 16],        Ab + ((size_t)st * 16 + kb) * 1024 + cl);
            async16(&As[buf * 8192 + 4096 + tid * 16], Ab + ((size_t)(st + 4) * 16 + kb) * 1024 + cl);
            async16(&Bs[buf * 8192 + tid * 16],        Bb + ((size_t)st * 16 + kb) * 1024 + cl);
            async16(&Bs[buf * 8192 + 4096 + tid * 16], Bb + ((size_t)(st + 4) * 16 + kb) * 1024 + cl);
        };

        stage(0, 0);
        asm volatile("s_waitcnt vmcnt(0)" ::: "memory");
        __builtin_amdgcn_s_barrier();
        for (int kb = 0; kb < 16; kb++) {
            const int cur = kb & 1;
            if (kb < 15) {
                stage(cur ^ 1, kb + 1);
                // retire tile-kb's 4 loads (oldest); kb+1's 4 stay in flight
                asm volatile("s_waitcnt vmcnt(4)" ::: "memory");
            } else {
                asm volatile("s_waitcnt vmcnt(0)" ::: "memory");
            }
            __builtin_amdgcn_s_barrier();   // all waves' cur-tile DMA landed

            lx2 a8[4], b8[4];
#pragma unroll
            for (int mt = 0; mt < 4; mt++)
                a8[mt] = *(const lx2*)&As[cur * 8192 + (stA + mt) * 1024 + lane * 16];
#pragma unroll
            for (int nt = 0; nt < 4; nt++)
                b8[nt] = *(const lx2*)&Bs[cur * 8192 + (stB + nt) * 1024 + lane * 16];
#pragma unroll
            for (int mt = 0; mt < 4; mt++)
#pragma unroll
                for (int nt = 0; nt < 4; nt++) {
                    acc[mt][nt] = __builtin_amdgcn_mfma_f32_16x16x32_fp8_fp8(
                        a8[mt].x, b8[nt].x, acc[mt][nt], 0, 0, 0);
                    acc[mt][nt] = __builtin_amdgcn_mfma_f32_16x16x32_fp8_fp8(
                        a8[mt].y, b8[nt].y, acc[mt][nt], 0, 0, 0);
                }
            // reads of buf[cur] retired before anyone overwrites it next iter
            asm volatile("s_waitcnt lgkmcnt(0)" ::: "memory");
            __builtin_amdgcn_sched_barrier(0);
            __builtin_amdgcn_s_barrier();
        }

#pragma unroll
        for (int mt = 0; mt < 4; mt++)
#pragma unroll
            for (int nt = 0; nt < 4; nt++)
#pragma unroll
                for (int r = 0; r < 4; r++) {
                    const int row = m0 + wm + mt * 16 + quad * 4 + r;
                    const int col = n0 + wn + nt * 16 + l16;
                    wkt_b[(size_t)row * 1024 + col] =
                        f2bf(fast_tanh(acc[mt][nt][r] * (1.0f / 512.0f)));
                }
    } else if (role == 1) {
        // ---- qproj bf16 GEMM: qproj = Qb @ WQb^T (512 x 1024, K=1024) -------
        unsigned short* As = (unsigned short*)smem;            // 8 KB
        unsigned short* Bs = (unsigned short*)(smem + 8192);   // 8 KB
        const int q = rb_;
        const int m0 = (q & 3) * 128;
        const int n0 = (q >> 2) * 128;
        const int wm = (wid >> 1) * 64;
        const int wn = (wid & 1) * 64;

        f32x4 acc[4][4] = {};
        const int r0 = tid >> 2;
        const int cc0 = (tid & 3) * 8;

        for (int k0 = 0; k0 < 1024; k0 += 32) {
            async16(&As[tid * 8],        Qb  + (size_t)(m0 + r0) * 1024 + k0 + cc0);
            async16(&As[2048 + tid * 8], Qb  + (size_t)(m0 + 64 + r0) * 1024 + k0 + cc0);
            async16(&Bs[tid * 8],        WQb + (size_t)(n0 + r0) * 1024 + k0 + cc0);
            async16(&Bs[2048 + tid * 8], WQb + (size_t)(n0 + 64 + r0) * 1024 + k0 + cc0);
            __syncthreads();

            bf16x8 af[4], bfr[4];
#pragma unroll
            for (int mt = 0; mt < 4; mt++)
                af[mt] = *(const bf16x8*)&As[(wm + mt * 16 + l16) * 32 + quad * 8];
#pragma unroll
            for (int nt = 0; nt < 4; nt++)
                bfr[nt] = *(const bf16x8*)&Bs[(wn + nt * 16 + l16) * 32 + quad * 8];
#pragma unroll
            for (int mt = 0; mt < 4; mt++)
#pragma unroll
                for (int nt = 0; nt < 4; nt++)
                    acc[mt][nt] = __builtin_amdgcn_mfma_f32_16x16x32_bf16(
                        af[mt], bfr[nt], acc[mt][nt], 0, 0, 0);
            __syncthreads();
        }

#pragma unroll
        for (int mt = 0; mt < 4; mt++)
#pragma unroll
            for (int nt = 0; nt < 4; nt++)
#pragma unroll
                for (int r = 0; r < 4; r++) {
                    const int row = m0 + wm + mt * 16 + quad * 4 + r;
                    const int col = n0 + wn + nt * 16 + l16;
                    qproj_b[(size_t)row * 1024 + col] = f2bf(acc[mt][nt][r]);
                }
    } else {
        // ---- kv GEMM: kv[((b*16+z)*32+c)*512+t] = sum_h tanh(H)*wql --------
        unsigned short* Ks = (unsigned short*)smem;             // 16 KB [tl][h]
        float* kvt = (float*)(smem + 16384);                    // 16.9 KB [tl][c] pad
        const int q = rb_;
        const int chunk = q & 127;
        const int z = q >> 7;
        const int b = chunk >> 2;
        const int t0 = (chunk & 3) * 128;

#pragma unroll
        for (int it = 0; it < 8; it++) {
            const int idx = it * 256 + tid;
            const int row = idx >> 4;
            const int c4 = (idx & 15) * 4;
            float4 v = *(const float4*)(H + ((size_t)b * T_LEN + t0 + row) * D_MODEL + z * D_K + c4);
            v = fast_tanh4(v);
            ushort4 o;
            o.x = f2bf(v.x); o.y = f2bf(v.y); o.z = f2bf(v.z); o.w = f2bf(v.w);
            *(ushort4*)&Ks[row * 64 + c4] = o;
        }
        bf16x8 bfr[2][2];
#pragma unroll
        for (int ct = 0; ct < 2; ct++)
#pragma unroll
            for (int kh = 0; kh < 2; kh++)
                bfr[ct][kh] = bf8_from_f32(wql +
                    (size_t)(ct * 16 + l16) * D_MODEL + z * D_K + kh * 32 + quad * 8);
        __syncthreads();

        const int wt = wid * 32;
        f32x4 acc[2][2] = {};
#pragma unroll
        for (int tt = 0; tt < 2; tt++) {
            const bf16x8 a0 = *(const bf16x8*)&Ks[(wt + tt * 16 + l16) * 64 + quad * 8];
            const bf16x8 a1 = *(const bf16x8*)&Ks[(wt + tt * 16 + l16) * 64 + 32 + quad * 8];
#pragma unroll
            for (int ct = 0; ct < 2; ct++) {
                acc[tt][ct] = __builtin_amdgcn_mfma_f32_16x16x32_bf16(a0, bfr[ct][0], acc[tt][ct], 0, 0, 0);
                acc[tt][ct] = __builtin_amdgcn_mfma_f32_16x16x32_bf16(a1, bfr[ct][1], acc[tt][ct], 0, 0, 0);
            }
        }
#pragma unroll
        for (int tt = 0; tt < 2; tt++)
#pragma unroll
            for (int ct = 0; ct < 2; ct++)
#pragma unroll
                for (int r = 0; r < 4; r++)
                    kvt[(wt + tt * 16 + quad * 4 + r) * 33 + ct * 16 + l16] = acc[tt][ct][r];
        __syncthreads();

        float* outb = kv + (((size_t)b * 16 + z) * 32) * 512 + t0;
#pragma unroll
        for (int it = 0; it < 4; it++) {
            const int idx = it * 256 + tid;
            const int c = idx >> 5;
            const int tq = (idx & 31) * 4;
            float4 v = make_float4(kvt[(tq + 0) * 33 + c], kvt[(tq + 1) * 33 + c],
                                   kvt[(tq + 2) * 33 + c], kvt[(tq + 3) * 33 + c]);
            *(float4*)(outb + (size_t)c * 512 + tq) = v;
        }
    }
}

// ================= attn: block per (b,z), 8 waves x 4 c-tiles ===============
// 512 threads, 64 KB LDS, 2 blocks/CU. 2-deep MFMA pipeline + 2-deep kv
// prefetch (round-11 A/B vs round 8: ~neutral within noise; kept frozen).
__global__ __launch_bounds__(512, 4) void attn_mfma(
    const unsigned short* __restrict__ qproj, const unsigned short* __restrict__ wkt,
    const float* __restrict__ kv, float* __restrict__ part)
{
    __shared__ unsigned short wkts[512 * 64];   // 64 KB, [t][k] swizzled
    const int z = blockIdx.x;
    const int b = blockIdx.y;
    const int tid = threadIdx.x;
    const int wid = tid >> 6;                   // 0..7
    const int lane = tid & 63;
    const int quad = lane >> 4;
    const int l16 = lane & 15;

    const unsigned short* wb = wkt + (size_t)(b * T_LEN) * D_MODEL + z * D_K;
#pragma unroll
    for (int it = 0; it < 8; it++) {
        const int chunk = it * 512 + tid;
        const int row = chunk >> 3;     // t (0..511)
        const int c = chunk & 7;        // 16B chunk within 128B row
        // inverse-swizzled source: LDS(row,c) holds global chunk (c ^ (row&7))
        async16(&wkts[chunk * 8], wb + (size_t)row * D_MODEL + ((c ^ (row & 7)) * 8));
    }

    bf16x8 af[4][2];
#pragma unroll
    for (int ct = 0; ct < 4; ct++)
#pragma unroll
        for (int kh = 0; kh < 2; kh++)
            af[ct][kh] = *(const bf16x8*)(qproj +
                (size_t)((wid * 4 + ct) * 16 + l16) * D_MODEL + z * D_K + kh * 32 + quad * 8);
    __syncthreads();

    float den[4][4], num[4][4];
#pragma unroll
    for (int ct = 0; ct < 4; ct++)
#pragma unroll
        for (int r = 0; r < 4; r++) { den[ct][r] = 0.f; num[ct][r] = 0.f; }

    // per-lane kv base: kv[((b*16+z)*32 + wid*4 + ct)*512 + nt*16 + l16]
    const float* kvp = kv + (((size_t)b * 16 + z) * 32 + wid * 4) * 512 + l16;
    float kc[4], k1[4];
#pragma unroll
    for (int ct = 0; ct < 4; ct++) kc[ct] = kvp[ct * 512];
#pragma unroll
    for (int ct = 0; ct < 4; ct++) k1[ct] = kvp[ct * 512 + 16];

    const int x0 = (quad ^ (l16 & 7)) * 8;        // swizzled read: chunks 0..3
    const int x1 = ((quad ^ 4) ^ (l16 & 7)) * 8;  // swizzled read: chunks 4..7

    f32x4 a4A[4], a4B[4];
    {   // prologue: MFMA for tile 0 -> a4A
        const int rbase = l16 * 64;
        const bf16x8 b0 = *(const bf16x8*)&wkts[rbase + x0];
        const bf16x8 b1 = *(const bf16x8*)&wkts[rbase + x1];
        __builtin_amdgcn_s_setprio(1);
#pragma unroll
        for (int ct = 0; ct < 4; ct++) {
            f32x4 a = {};
            a = __builtin_amdgcn_mfma_f32_16x16x32_bf16(af[ct][0], b0, a, 0, 0, 0);
            a = __builtin_amdgcn_mfma_f32_16x16x32_bf16(af[ct][1], b1, a, 0, 0, 0);
            a4A[ct] = a;
        }
        __builtin_amdgcn_s_setprio(0);
    }

    for (int nt = 0; nt < 32; nt += 2) {
        // ---- phase A: consume a4A with kv[nt]; load kv[nt+2]; MFMA(nt+1)->a4B
        {
            const int rb1 = ((nt + 1) * 16 + l16) * 64;
            const bf16x8 c0 = *(const bf16x8*)&wkts[rb1 + x0];
            const bf16x8 c1 = *(const bf16x8*)&wkts[rb1 + x1];
            float k2[4];
#pragma unroll
            for (int ct = 0; ct < 4; ct++) k2[ct] = kvp[ct * 512 + (nt + 2) * 16];
#pragma unroll
            for (int ct = 0; ct < 4; ct++)
#pragma unroll
                for (int r = 0; r < 4; r++) {
                    const float e = exp2_fast(a4A[ct][r]);
                    den[ct][r] += e;
                    num[ct][r] += e * kc[ct];
                }
            __builtin_amdgcn_s_setprio(1);
#pragma unroll
            for (int ct = 0; ct < 4; ct++) {
                f32x4 a = {};
                a = __builtin_amdgcn_mfma_f32_16x16x32_bf16(af[ct][0], c0, a, 0, 0, 0);
                a = __builtin_amdgcn_mfma_f32_16x16x32_bf16(af[ct][1], c1, a, 0, 0, 0);
                a4B[ct] = a;
            }
            __builtin_amdgcn_s_setprio(0);
#pragma unroll
            for (int ct = 0; ct < 4; ct++) { kc[ct] = k1[ct]; k1[ct] = k2[ct]; }
        }
        // ---- phase B: consume a4B with kv[nt+1]; load kv[nt+3]; MFMA(nt+2)->a4A
        {
            const bool more = (nt + 2) < 32;
            bf16x8 d0 = {}, d1 = {};
            if (more) {
                const int rb2 = ((nt + 2) * 16 + l16) * 64;
                d0 = *(const bf16x8*)&wkts[rb2 + x0];
                d1 = *(const bf16x8*)&wkts[rb2 + x1];
            }
            float k3[4];
#pragma unroll
            for (int ct = 0; ct < 4; ct++) k3[ct] = kvp[ct * 512 + (nt + 3) * 16];
#pragma unroll
            for (int ct = 0; ct < 4; ct++)
#pragma unroll
                for (int r = 0; r < 4; r++) {
                    const float e = exp2_fast(a4B[ct][r]);
                    den[ct][r] += e;
                    num[ct][r] += e * kc[ct];
                }
            if (more) {
                __builtin_amdgcn_s_setprio(1);
#pragma unroll
                for (int ct = 0; ct < 4; ct++) {
                    f32x4 a = {};
                    a = __builtin_amdgcn_mfma_f32_16x16x32_bf16(af[ct][0], d0, a, 0, 0, 0);
                    a = __builtin_amdgcn_mfma_f32_16x16x32_bf16(af[ct][1], d1, a, 0, 0, 0);
                    a4A[ct] = a;
                }
                __builtin_amdgcn_s_setprio(0);
            }
#pragma unroll
            for (int ct = 0; ct < 4; ct++) { kc[ct] = k1[ct]; k1[ct] = k3[ct]; }
        }
    }

#pragma unroll
    for (int ct = 0; ct < 4; ct++) {
        float s = 0.f;
#pragma unroll
        for (int r = 0; r < 4; r++) {
            float d = den[ct][r], n = num[ct][r];
#pragma unroll
            for (int off = 1; off < 16; off <<= 1) {
                d += __shfl_xor(d, off, 64);
                n += __shfl_xor(n, off, 64);
            }
            s += n / d;
        }
        s += __shfl_xor(s, 16, 64);
        s += __shfl_xor(s, 32, 64);
        if (lane == 0)
            part[((size_t)(b * N_CLASSES) + wid * 4 + ct) * 16 + z] = s;
    }
}

// ---------------- combine z + apply 1/16 s-mean: out[b,c] -------------------
__global__ __launch_bounds__(256) void attn_reduce(
    const float* __restrict__ part, float* __restrict__ out)
{
    const int i = blockIdx.x * 256 + threadIdx.x;   // bc in [0,1024)
    const float* p = part + (size_t)i * 16;
    float s = 0.f;
#pragma unroll
    for (int zz = 0; zz < 16; zz++) s += p[zz];
    out[i] = s * (1.0f / 16.0f);
}

extern "C" void kernel_launch(void* const* d_in, const int* in_sizes, int n_in,
                              void* d_out, int out_size, void* d_ws, size_t ws_size,
                              hipStream_t stream)
{
    const float* Q  = (const float*)d_in[0];   // (32,16,1024)
    const float* H  = (const float*)d_in[1];   // (32,512,1024)
    const float* ql = (const float*)d_in[2];   // (32,1024)
    const float* WQ = (const float*)d_in[3];   // (1024,1024)
    const float* WK = (const float*)d_in[4];
    const float* WV = (const float*)d_in[5];
    float* out = (float*)d_out;                // (32,32)

    char* ws = (char*)d_ws;
    // Flat layout (no overlays, peak ~101 MB):
    //   0        : Hf8      (16.78 MB)
    //   24MB     : Qb       (1 MB)
    //   25MB     : WQb      (2 MB)
    //   27MB     : qproj_b  (1 MB)
    //   29MB     : part     (64 KB)
    //   30MB     : wqlb f32 (128 KB)
    //   32MB     : wkt_b    (33.5 MB)
    //   64MB     : kv       (33.5 MB)
    //   96MB     : WKf8     (1 MB)
    unsigned char*  Hf8     = (unsigned char*)(ws);
    unsigned short* Qb      = (unsigned short*)(ws + (size_t)25165824);
    unsigned short* WQb     = (unsigned short*)(ws + (size_t)26214400);
    unsigned short* qproj_b = (unsigned short*)(ws + (size_t)28311552);
    float*          part    = (float*)(ws + (size_t)30408704);
    float*          wqlb    = (float*)(ws + (size_t)31457280);
    unsigned short* wkt_b   = (unsigned short*)(ws + (size_t)33554432);
    float*          kv      = (float*)(ws + (size_t)67108864);
    unsigned char*  WKf8    = (unsigned char*)(ws + (size_t)100663296);

    dim3 thr(256);
    // wqlb zero for split-K atomics
    hipMemsetAsync(wqlb, 0, (size_t)N_CLASSES * D_MODEL * sizeof(float), stream);
    // prep: wql (256, split-K) + fp8 cvt (4352) + bf16 cvt (1536) = 6144
    prep_kernel<<<dim3(6144), thr, 0, stream>>>(
        H, (int*)Hf8, WK, (int*)WKf8,
        (const float4*)Q, (ushort4*)Qb,
        (const float4*)WQ, (ushort4*)WQb,
        ql, WV, wqlb);
    // gemms: 32 qproj first, then 1:2 interleave of fp8 (1024) : kv (2048)
    gemms_kernel<<<dim3(3104), thr, 0, stream>>>(
        Hf8, WKf8, wkt_b, Qb, WQb, qproj_b, H, wqlb, kv);
    // fused scores -> exp2 -> num/den partials per (b,c,z)
    attn_mfma<<<dim3(16, 32), dim3(512), 0, stream>>>(qproj_b, wkt_b, kv, part);
    // combine z + 1/16 s-mean
    attn_reduce<<<dim3(4), thr, 0, stream>>>(part, out);
}

// Round 13
// 195.815 us; speedup vs baseline: 1.0276x; 1.0276x over previous
//
#include <hip/hip_runtime.h>
#include <hip/hip_bf16.h>
#include <math.h>

#define D_MODEL 1024
#define N_HEADS 16
#define D_K 64
#define N_CLASSES 32
#define S_LEN 16
#define BATCH 32
#define T_LEN 512

typedef __bf16 bf16_t;
typedef bf16_t bf16x8 __attribute__((ext_vector_type(8)));
typedef float f32x4 __attribute__((ext_vector_type(4)));
typedef long lx2 __attribute__((ext_vector_type(2)));

__device__ inline unsigned short f2bf(float f) {
    unsigned int u = __float_as_uint(f);
    unsigned int r = (u + 0x7FFFu + ((u >> 16) & 1u)) >> 16;   // RNE
    return (unsigned short)r;
}
// fast tanh: (e-1)/(e+1), e = exp(2x). Valid for |x| < 40. rel err ~1e-6.
__device__ inline float fast_tanh(float x) {
    float e = __expf(2.0f * x);
    return (e - 1.0f) * __builtin_amdgcn_rcpf(e + 1.0f);
}
__device__ inline float4 fast_tanh4(float4 v) {
    return make_float4(fast_tanh(v.x), fast_tanh(v.y), fast_tanh(v.z), fast_tanh(v.w));
}
__device__ inline float dot4(float4 a, float4 b) {
    return a.x * b.x + a.y * b.y + a.z * b.z + a.w * b.w;
}
// bare v_exp_f32: D = 2^x (scores pre-scaled by log2e via Q)
__device__ inline float exp2_fast(float x) {
    float r;
    asm("v_exp_f32 %0, %1" : "=v"(r) : "v"(x));
    return r;
}
// pack 4 floats -> 4 e4m3 bytes (OCP, HW cvt)
__device__ inline int pack_fp8x4(float4 v) {
    int p = __builtin_amdgcn_cvt_pk_fp8_f32(v.x, v.y, 0, false);
    p = __builtin_amdgcn_cvt_pk_fp8_f32(v.z, v.w, p, true);
    return p;
}
// 8 consecutive f32 -> bf16x8 fragment
__device__ inline bf16x8 bf8_from_f32(const float* p) {
    float4 a = *(const float4*)p;
    float4 b = *(const float4*)(p + 4);
    union { bf16x8 v; unsigned short s[8]; } u;
    u.s[0] = f2bf(a.x); u.s[1] = f2bf(a.y); u.s[2] = f2bf(a.z); u.s[3] = f2bf(a.w);
    u.s[4] = f2bf(b.x); u.s[5] = f2bf(b.y); u.s[6] = f2bf(b.z); u.s[7] = f2bf(b.w);
    return u.v;
}

// async global->LDS, 16 bytes per lane (global_load_lds_dwordx4)
__device__ inline void async16(void* lds, const void* g) {
    __builtin_amdgcn_global_load_lds(
        (const __attribute__((address_space(1))) unsigned int*)g,
        (__attribute__((address_space(3))) unsigned int*)lds, 16, 0, 0);
}

// ================= prep: wql-splitK ∥ fp8-swizzle cvt ∥ bf16 cvt ============
// ROUND-8-VERIFIED. wql must stay WIDE (256 split-K blocks + atomics) --
// twice-confirmed lesson (rounds 3 & 9): narrow wql rewrites create a serial
// tail; the memset is noise, the parallelism is not.
__global__ __launch_bounds__(256) void prep_kernel(
    const float* __restrict__ H, int* __restrict__ Hf8,
    const float* __restrict__ WK, int* __restrict__ WKf8,
    const float4* __restrict__ Q, ushort4* __restrict__ Qb,
    const float4* __restrict__ WQ, ushort4* __restrict__ WQb,
    const float* __restrict__ ql, const float* __restrict__ WV,
    float* __restrict__ wql)
{
    __shared__ __align__(16) char psm[25600];
    const int bid = blockIdx.x;
    const int tid = threadIdx.x;
    if (bid < 256) {
        // ---- wql split-K: wql[c][n] += sum_{k0..k0+63} ql[c][k]*WV[n][k] ----
        float4 (*qls)[16] = (float4(*)[16])psm;               // [32][16]  8 KB
        float4 (*WVs)[17] = (float4(*)[17])(psm + 8192);      // [64][17] 17.4 KB
        const int n0 = (bid & 15) * 64;
        const int k0 = (bid >> 4) * 64;
        for (int i = tid; i < 512; i += 256)
            qls[i >> 4][i & 15] = *(const float4*)(ql + (size_t)(i >> 4) * D_MODEL + k0 + (i & 15) * 4);
        for (int i = tid; i < 1024; i += 256)
            WVs[i >> 4][i & 15] = *(const float4*)(WV + (size_t)(n0 + (i >> 4)) * D_MODEL + k0 + (i & 15) * 4);
        __syncthreads();

        const int n = tid & 63;
        const int c0 = (tid >> 6) * 8;
        float acc[8] = {};
        for (int kq = 0; kq < 16; kq++) {
            const float4 wv = WVs[n][kq];
#pragma unroll
            for (int c = 0; c < 8; c++) acc[c] += dot4(qls[c0 + c][kq], wv);
        }
#pragma unroll
        for (int c = 0; c < 8; c++)
            atomicAdd(&wql[(size_t)(c0 + c) * D_MODEL + n0 + n], acc[c]);
    } else if (bid < 4608) {
        // ---- LDS-mediated fp8 swizzle cvt: H (4096 CTAs), WK (256 CTAs) ----
        float (*L)[260] = (float(*)[260])psm;   // 16 x 260 floats = 16.6 KB
        int j = bid - 256;
        const float* in; int* out; float s; int jj;
        if (j < 4096) { in = H; out = Hf8; s = 1.0f; jj = j; }
        else { in = WK; out = WKf8; s = 512.0f; jj = j - 4096; }
        const int rb = jj >> 2;
        const int kb0 = (jj & 3) * 4;
        const float* base = in + (size_t)rb * 16 * 1024 + kb0 * 64;
#pragma unroll
        for (int it = 0; it < 4; it++) {
            const int idx = it * 256 + tid;
            const int row = idx >> 6;            // 0..15
            const int c0 = (idx & 63) * 4;       // 0..252
            *(float4*)&L[row][c0] = *(const float4*)(base + (size_t)row * 1024 + c0);
        }
        __syncthreads();
        const int quad = tid >> 6;
        const int l16 = (tid >> 2) & 15;
        const int kh = (tid & 3) >> 1;
        const int b0 = (tid & 1) * 4;
        const int klb = kh * 32 + quad * 8 + b0;
        int* outp = out + (size_t)jj * 1024 + tid;
#pragma unroll
        for (int p = 0; p < 4; p++) {
            float4 v = *(const float4*)&L[l16][p * 64 + klb];
            v.x *= s; v.y *= s; v.z *= s; v.w *= s;
            outp[p * 256] = pack_fp8x4(v);
        }
    } else {
        // ---- bf16 cvt: Q (131072 float4, x log2e), WQ (262144 float4) ------
        int i = (bid - 4608) * 256 + tid;
        const float4* in; ushort4* out; float s;
        if (i < 131072) { in = Q + i; out = Qb + i; s = 1.4426950408889634f; }
        else { i -= 131072; in = WQ + i; out = WQb + i; s = 1.0f; }
        float4 v = *in;
        ushort4 o;
        o.x = f2bf(v.x * s); o.y = f2bf(v.y * s); o.z = f2bf(v.z * s); o.w = f2bf(v.w * s);
        *out = o;
    }
}

// ================= gemms: fp8 GEMM ∥ qproj bf16 GEMM ∥ kv GEMM ==============
// Role-mixed dispatch, CHUNKED this round: qproj's 32 long blocks first, then
// 128 groups of {8 fp8, 16 kv}. R12's fine 1:2 interleave won overlap (-3.2us
// on gemms) but broke fp8's L2 panel reuse (FETCH 61->98 MB). Chunks of 8
// m-consecutive same-n fp8 blocks keep the 1MB B-panel (the 128x-re-read
// operand) L2-hot within each group while CUs still co-host both roles.
__global__ __launch_bounds__(256) void gemms_kernel(
    const unsigned char* __restrict__ A8, const unsigned char* __restrict__ B8,
    unsigned short* __restrict__ wkt_b,
    const unsigned short* __restrict__ Qb, const unsigned short* __restrict__ WQb,
    unsigned short* __restrict__ qproj_b,
    const float* __restrict__ H, const float* __restrict__ wql,
    float* __restrict__ kv)
{
    __shared__ __align__(16) char smem[33280];
    const int bid = blockIdx.x;
    const int tid = threadIdx.x;
    const int wid = tid >> 6;
    const int lane = tid & 63;
    const int quad = lane >> 4;
    const int l16 = lane & 15;

    // role decode: 32 qproj first, then 128 groups of {8 fp8, 16 kv}
    int role, rb_;
    if (bid < 32) { role = 1; rb_ = bid; }
    else {
        const int j = bid - 32;          // 0..3071
        const int g = j / 24;            // group 0..127
        const int r = j % 24;
        if (r < 8) { role = 0; rb_ = g * 8 + r; }        // fp8: 0..1023
        else       { role = 2; rb_ = g * 16 + (r - 8); } // kv: 0..2047
    }

    if (role == 0) {
        // ---- fp8 GEMM: wkt = bf16(fast_tanh((H8 @ WK8^T)/512)), 16384x1024 ---
        unsigned char* As = (unsigned char*)smem;           // 2 x 8 KB
        unsigned char* Bs = (unsigned char*)smem + 16384;   // 2 x 8 KB
        const int m0 = (rb_ & 127) * 128;   // m-fast grid (round-8-verified)
        const int n0 = (rb_ >> 7) * 128;
        const int wm = (wid >> 1) * 64;
        const int wn = (wid & 1) * 64;
        const int stA = wm >> 4;
        const int stB = wn >> 4;
        const int st = wid;
        const int cl = lane * 16;

        f32x4 acc[4][4] = {};
        const unsigned char* Ab = A8 + ((size_t)(m0 >> 4) * 16) * 1024;
        const unsigned char* Bb = B8 + ((size_t)(n0 >> 4) * 16) * 1024;

        auto stage = [&](int buf, int kb) {
            async16(&As[buf * 8192 + tid * 16],        Ab + ((size_t)st * 16 + kb) * 1024 + cl);
            async16(&As[buf * 8192 + 4096 + tid * 16], Ab + ((size_t)(st + 4) * 16 + kb) * 1024 + cl);
            async16(&Bs[buf * 8192 + tid * 16],        Bb + ((size_t)st * 16 + kb) * 1024 + cl);
            async16(&Bs[buf * 8192 + 4096 + tid * 16], Bb + ((size_t)(st + 4) * 16 + kb) * 1024 + cl);
        };

        stage(0, 0);
        asm volatile("s_waitcnt vmcnt(0)" ::: "memory");
        __builtin_amdgcn_s_barrier();
        for (int kb = 0; kb < 16; kb++) {
            const int cur = kb & 1;
            if (kb < 15) {
                stage(cur ^ 1, kb + 1);
                // retire tile-kb's 4 loads (oldest); kb+1's 4 stay in flight
                asm volatile("s_waitcnt vmcnt(4)" ::: "memory");
            } else {
                asm volatile("s_waitcnt vmcnt(0)" ::: "memory");
            }
            __builtin_amdgcn_s_barrier();   // all waves' cur-tile DMA landed

            lx2 a8[4], b8[4];
#pragma unroll
            for (int mt = 0; mt < 4; mt++)
                a8[mt] = *(const lx2*)&As[cur * 8192 + (stA + mt) * 1024 + lane * 16];
#pragma unroll
            for (int nt = 0; nt < 4; nt++)
                b8[nt] = *(const lx2*)&Bs[cur * 8192 + (stB + nt) * 1024 + lane * 16];
#pragma unroll
            for (int mt = 0; mt < 4; mt++)
#pragma unroll
                for (int nt = 0; nt < 4; nt++) {
                    acc[mt][nt] = __builtin_amdgcn_mfma_f32_16x16x32_fp8_fp8(
                        a8[mt].x, b8[nt].x, acc[mt][nt], 0, 0, 0);
                    acc[mt][nt] = __builtin_amdgcn_mfma_f32_16x16x32_fp8_fp8(
                        a8[mt].y, b8[nt].y, acc[mt][nt], 0, 0, 0);
                }
            // reads of buf[cur] retired before anyone overwrites it next iter
            asm volatile("s_waitcnt lgkmcnt(0)" ::: "memory");
            __builtin_amdgcn_sched_barrier(0);
            __builtin_amdgcn_s_barrier();
        }

#pragma unroll
        for (int mt = 0; mt < 4; mt++)
#pragma unroll
            for (int nt = 0; nt < 4; nt++)
#pragma unroll
                for (int r = 0; r < 4; r++) {
                    const int row = m0 + wm + mt * 16 + quad * 4 + r;
                    const int col = n0 + wn + nt * 16 + l16;
                    wkt_b[(size_t)row * 1024 + col] =
                        f2bf(fast_tanh(acc[mt][nt][r] * (1.0f / 512.0f)));
                }
    } else if (role == 1) {
        // ---- qproj bf16 GEMM: qproj = Qb @ WQb^T (512 x 1024, K=1024) -------
        unsigned short* As = (unsigned short*)smem;            // 8 KB
        unsigned short* Bs = (unsigned short*)(smem + 8192);   // 8 KB
        const int q = rb_;
        const int m0 = (q & 3) * 128;
        const int n0 = (q >> 2) * 128;
        const int wm = (wid >> 1) * 64;
        const int wn = (wid & 1) * 64;

        f32x4 acc[4][4] = {};
        const int r0 = tid >> 2;
        const int cc0 = (tid & 3) * 8;

        for (int k0 = 0; k0 < 1024; k0 += 32) {
            async16(&As[tid * 8],        Qb  + (size_t)(m0 + r0) * 1024 + k0 + cc0);
            async16(&As[2048 + tid * 8], Qb  + (size_t)(m0 + 64 + r0) * 1024 + k0 + cc0);
            async16(&Bs[tid * 8],        WQb + (size_t)(n0 + r0) * 1024 + k0 + cc0);
            async16(&Bs[2048 + tid * 8], WQb + (size_t)(n0 + 64 + r0) * 1024 + k0 + cc0);
            __syncthreads();

            bf16x8 af[4], bfr[4];
#pragma unroll
            for (int mt = 0; mt < 4; mt++)
                af[mt] = *(const bf16x8*)&As[(wm + mt * 16 + l16) * 32 + quad * 8];
#pragma unroll
            for (int nt = 0; nt < 4; nt++)
                bfr[nt] = *(const bf16x8*)&Bs[(wn + nt * 16 + l16) * 32 + quad * 8];
#pragma unroll
            for (int mt = 0; mt < 4; mt++)
#pragma unroll
                for (int nt = 0; nt < 4; nt++)
                    acc[mt][nt] = __builtin_amdgcn_mfma_f32_16x16x32_bf16(
                        af[mt], bfr[nt], acc[mt][nt], 0, 0, 0);
            __syncthreads();
        }

#pragma unroll
        for (int mt = 0; mt < 4; mt++)
#pragma unroll
            for (int nt = 0; nt < 4; nt++)
#pragma unroll
                for (int r = 0; r < 4; r++) {
                    const int row = m0 + wm + mt * 16 + quad * 4 + r;
                    const int col = n0 + wn + nt * 16 + l16;
                    qproj_b[(size_t)row * 1024 + col] = f2bf(acc[mt][nt][r]);
                }
    } else {
        // ---- kv GEMM: kv[((b*16+z)*32+c)*512+t] = sum_h tanh(H)*wql --------
        unsigned short* Ks = (unsigned short*)smem;             // 16 KB [tl][h]
        float* kvt = (float*)(smem + 16384);                    // 16.9 KB [tl][c] pad
        const int q = rb_;
        const int chunk = q & 127;
        const int z = q >> 7;
        const int b = chunk >> 2;
        const int t0 = (chunk & 3) * 128;

#pragma unroll
        for (int it = 0; it < 8; it++) {
            const int idx = it * 256 + tid;
            const int row = idx >> 4;
            const int c4 = (idx & 15) * 4;
            float4 v = *(const float4*)(H + ((size_t)b * T_LEN + t0 + row) * D_MODEL + z * D_K + c4);
            v = fast_tanh4(v);
            ushort4 o;
            o.x = f2bf(v.x); o.y = f2bf(v.y); o.z = f2bf(v.z); o.w = f2bf(v.w);
            *(ushort4*)&Ks[row * 64 + c4] = o;
        }
        bf16x8 bfr[2][2];
#pragma unroll
        for (int ct = 0; ct < 2; ct++)
#pragma unroll
            for (int kh = 0; kh < 2; kh++)
                bfr[ct][kh] = bf8_from_f32(wql +
                    (size_t)(ct * 16 + l16) * D_MODEL + z * D_K + kh * 32 + quad * 8);
        __syncthreads();

        const int wt = wid * 32;
        f32x4 acc[2][2] = {};
#pragma unroll
        for (int tt = 0; tt < 2; tt++) {
            const bf16x8 a0 = *(const bf16x8*)&Ks[(wt + tt * 16 + l16) * 64 + quad * 8];
            const bf16x8 a1 = *(const bf16x8*)&Ks[(wt + tt * 16 + l16) * 64 + 32 + quad * 8];
#pragma unroll
            for (int ct = 0; ct < 2; ct++) {
                acc[tt][ct] = __builtin_amdgcn_mfma_f32_16x16x32_bf16(a0, bfr[ct][0], acc[tt][ct], 0, 0, 0);
                acc[tt][ct] = __builtin_amdgcn_mfma_f32_16x16x32_bf16(a1, bfr[ct][1], acc[tt][ct], 0, 0, 0);
            }
        }
#pragma unroll
        for (int tt = 0; tt < 2; tt++)
#pragma unroll
            for (int ct = 0; ct < 2; ct++)
#pragma unroll
                for (int r = 0; r < 4; r++)
                    kvt[(wt + tt * 16 + quad * 4 + r) * 33 + ct * 16 + l16] = acc[tt][ct][r];
        __syncthreads();

        float* outb = kv + (((size_t)b * 16 + z) * 32) * 512 + t0;
#pragma unroll
        for (int it = 0; it < 4; it++) {
            const int idx = it * 256 + tid;
            const int c = idx >> 5;
            const int tq = (idx & 31) * 4;
            float4 v = make_float4(kvt[(tq + 0) * 33 + c], kvt[(tq + 1) * 33 + c],
                                   kvt[(tq + 2) * 33 + c], kvt[(tq + 3) * 33 + c]);
            *(float4*)(outb + (size_t)c * 512 + tq) = v;
        }
    }
}

// ================= attn: block per (b,z), 8 waves x 4 c-tiles ===============
// 512 threads, 64 KB LDS, 2 blocks/CU. 2-deep MFMA pipeline + 2-deep kv
// prefetch. FROZEN from round 12.
__global__ __launch_bounds__(512, 4) void attn_mfma(
    const unsigned short* __restrict__ qproj, const unsigned short* __restrict__ wkt,
    const float* __restrict__ kv, float* __restrict__ part)
{
    __shared__ unsigned short wkts[512 * 64];   // 64 KB, [t][k] swizzled
    const int z = blockIdx.x;
    const int b = blockIdx.y;
    const int tid = threadIdx.x;
    const int wid = tid >> 6;                   // 0..7
    const int lane = tid & 63;
    const int quad = lane >> 4;
    const int l16 = lane & 15;

    const unsigned short* wb = wkt + (size_t)(b * T_LEN) * D_MODEL + z * D_K;
#pragma unroll
    for (int it = 0; it < 8; it++) {
        const int chunk = it * 512 + tid;
        const int row = chunk >> 3;     // t (0..511)
        const int c = chunk & 7;        // 16B chunk within 128B row
        // inverse-swizzled source: LDS(row,c) holds global chunk (c ^ (row&7))
        async16(&wkts[chunk * 8], wb + (size_t)row * D_MODEL + ((c ^ (row & 7)) * 8));
    }

    bf16x8 af[4][2];
#pragma unroll
    for (int ct = 0; ct < 4; ct++)
#pragma unroll
        for (int kh = 0; kh < 2; kh++)
            af[ct][kh] = *(const bf16x8*)(qproj +
                (size_t)((wid * 4 + ct) * 16 + l16) * D_MODEL + z * D_K + kh * 32 + quad * 8);
    __syncthreads();

    float den[4][4], num[4][4];
#pragma unroll
    for (int ct = 0; ct < 4; ct++)
#pragma unroll
        for (int r = 0; r < 4; r++) { den[ct][r] = 0.f; num[ct][r] = 0.f; }

    // per-lane kv base: kv[((b*16+z)*32 + wid*4 + ct)*512 + nt*16 + l16]
    const float* kvp = kv + (((size_t)b * 16 + z) * 32 + wid * 4) * 512 + l16;
    float kc[4], k1[4];
#pragma unroll
    for (int ct = 0; ct < 4; ct++) kc[ct] = kvp[ct * 512];
#pragma unroll
    for (int ct = 0; ct < 4; ct++) k1[ct] = kvp[ct * 512 + 16];

    const int x0 = (quad ^ (l16 & 7)) * 8;        // swizzled read: chunks 0..3
    const int x1 = ((quad ^ 4) ^ (l16 & 7)) * 8;  // swizzled read: chunks 4..7

    f32x4 a4A[4], a4B[4];
    {   // prologue: MFMA for tile 0 -> a4A
        const int rbase = l16 * 64;
        const bf16x8 b0 = *(const bf16x8*)&wkts[rbase + x0];
        const bf16x8 b1 = *(const bf16x8*)&wkts[rbase + x1];
        __builtin_amdgcn_s_setprio(1);
#pragma unroll
        for (int ct = 0; ct < 4; ct++) {
            f32x4 a = {};
            a = __builtin_amdgcn_mfma_f32_16x16x32_bf16(af[ct][0], b0, a, 0, 0, 0);
            a = __builtin_amdgcn_mfma_f32_16x16x32_bf16(af[ct][1], b1, a, 0, 0, 0);
            a4A[ct] = a;
        }
        __builtin_amdgcn_s_setprio(0);
    }

    for (int nt = 0; nt < 32; nt += 2) {
        // ---- phase A: consume a4A with kv[nt]; load kv[nt+2]; MFMA(nt+1)->a4B
        {
            const int rb1 = ((nt + 1) * 16 + l16) * 64;
            const bf16x8 c0 = *(const bf16x8*)&wkts[rb1 + x0];
            const bf16x8 c1 = *(const bf16x8*)&wkts[rb1 + x1];
            float k2[4];
#pragma unroll
            for (int ct = 0; ct < 4; ct++) k2[ct] = kvp[ct * 512 + (nt + 2) * 16];
#pragma unroll
            for (int ct = 0; ct < 4; ct++)
#pragma unroll
                for (int r = 0; r < 4; r++) {
                    const float e = exp2_fast(a4A[ct][r]);
                    den[ct][r] += e;
                    num[ct][r] += e * kc[ct];
                }
            __builtin_amdgcn_s_setprio(1);
#pragma unroll
            for (int ct = 0; ct < 4; ct++) {
                f32x4 a = {};
                a = __builtin_amdgcn_mfma_f32_16x16x32_bf16(af[ct][0], c0, a, 0, 0, 0);
                a = __builtin_amdgcn_mfma_f32_16x16x32_bf16(af[ct][1], c1, a, 0, 0, 0);
                a4B[ct] = a;
            }
            __builtin_amdgcn_s_setprio(0);
#pragma unroll
            for (int ct = 0; ct < 4; ct++) { kc[ct] = k1[ct]; k1[ct] = k2[ct]; }
        }
        // ---- phase B: consume a4B with kv[nt+1]; load kv[nt+3]; MFMA(nt+2)->a4A
        {
            const bool more = (nt + 2) < 32;
            bf16x8 d0 = {}, d1 = {};
            if (more) {
                const int rb2 = ((nt + 2) * 16 + l16) * 64;
                d0 = *(const bf16x8*)&wkts[rb2 + x0];
                d1 = *(const bf16x8*)&wkts[rb2 + x1];
            }
            float k3[4];
#pragma unroll
            for (int ct = 0; ct < 4; ct++) k3[ct] = kvp[ct * 512 + (nt + 3) * 16];
#pragma unroll
            for (int ct = 0; ct < 4; ct++)
#pragma unroll
                for (int r = 0; r < 4; r++) {
                    const float e = exp2_fast(a4B[ct][r]);
                    den[ct][r] += e;
                    num[ct][r] += e * kc[ct];
                }
            if (more) {
                __builtin_amdgcn_s_setprio(1);
#pragma unroll
                for (int ct = 0; ct < 4; ct++) {
                    f32x4 a = {};
                    a = __builtin_amdgcn_mfma_f32_16x16x32_bf16(af[ct][0], d0, a, 0, 0, 0);
                    a = __builtin_amdgcn_mfma_f32_16x16x32_bf16(af[ct][1], d1, a, 0, 0, 0);
                    a4A[ct] = a;
                }
                __builtin_amdgcn_s_setprio(0);
            }
#pragma unroll
            for (int ct = 0; ct < 4; ct++) { kc[ct] = k1[ct]; k1[ct] = k3[ct]; }
        }
    }

#pragma unroll
    for (int ct = 0; ct < 4; ct++) {
        float s = 0.f;
#pragma unroll
        for (int r = 0; r < 4; r++) {
            float d = den[ct][r], n = num[ct][r];
#pragma unroll
            for (int off = 1; off < 16; off <<= 1) {
                d += __shfl_xor(d, off, 64);
                n += __shfl_xor(n, off, 64);
            }
            s += n / d;
        }
        s += __shfl_xor(s, 16, 64);
        s += __shfl_xor(s, 32, 64);
        if (lane == 0)
            part[((size_t)(b * N_CLASSES) + wid * 4 + ct) * 16 + z] = s;
    }
}

// ---------------- combine z + apply 1/16 s-mean: out[b,c] -------------------
__global__ __launch_bounds__(256) void attn_reduce(
    const float* __restrict__ part, float* __restrict__ out)
{
    const int i = blockIdx.x * 256 + threadIdx.x;   // bc in [0,1024)
    const float* p = part + (size_t)i * 16;
    float s = 0.f;
#pragma unroll
    for (int zz = 0; zz < 16; zz++) s += p[zz];
    out[i] = s * (1.0f / 16.0f);
}

extern "C" void kernel_launch(void* const* d_in, const int* in_sizes, int n_in,
                              void* d_out, int out_size, void* d_ws, size_t ws_size,
                              hipStream_t stream)
{
    const float* Q  = (const float*)d_in[0];   // (32,16,1024)
    const float* H  = (const float*)d_in[1];   // (32,512,1024)
    const float* ql = (const float*)d_in[2];   // (32,1024)
    const float* WQ = (const float*)d_in[3];   // (1024,1024)
    const float* WK = (const float*)d_in[4];
    const float* WV = (const float*)d_in[5];
    float* out = (float*)d_out;                // (32,32)

    char* ws = (char*)d_ws;
    // Flat layout (no overlays, peak ~101 MB):
    //   0        : Hf8      (16.78 MB)
    //   24MB     : Qb       (1 MB)
    //   25MB     : WQb      (2 MB)
    //   27MB     : qproj_b  (1 MB)
    //   29MB     : part     (64 KB)
    //   30MB     : wqlb f32 (128 KB)
    //   32MB     : wkt_b    (33.5 MB)
    //   64MB     : kv       (33.5 MB)
    //   96MB     : WKf8     (1 MB)
    unsigned char*  Hf8     = (unsigned char*)(ws);
    unsigned short* Qb      = (unsigned short*)(ws + (size_t)25165824);
    unsigned short* WQb     = (unsigned short*)(ws + (size_t)26214400);
    unsigned short* qproj_b = (unsigned short*)(ws + (size_t)28311552);
    float*          part    = (float*)(ws + (size_t)30408704);
    float*          wqlb    = (float*)(ws + (size_t)31457280);
    unsigned short* wkt_b   = (unsigned short*)(ws + (size_t)33554432);
    float*          kv      = (float*)(ws + (size_t)67108864);
    unsigned char*  WKf8    = (unsigned char*)(ws + (size_t)100663296);

    dim3 thr(256);
    // wqlb zero for split-K atomics
    hipMemsetAsync(wqlb, 0, (size_t)N_CLASSES * D_MODEL * sizeof(float), stream);
    // prep: wql (256, split-K) + fp8 cvt (4352) + bf16 cvt (1536) = 6144
    prep_kernel<<<dim3(6144), thr, 0, stream>>>(
        H, (int*)Hf8, WK, (int*)WKf8,
        (const float4*)Q, (ushort4*)Qb,
        (const float4*)WQ, (ushort4*)WQb,
        ql, WV, wqlb);
    // gemms: 32 qproj first, then 128 groups of {8 fp8, 16 kv}
    gemms_kernel<<<dim3(3104), thr, 0, stream>>>(
        Hf8, WKf8, wkt_b, Qb, WQb, qproj_b, H, wqlb, kv);
    // fused scores -> exp2 -> num/den partials per (b,c,z)
    attn_mfma<<<dim3(16, 32), dim3(512), 0, stream>>>(qproj_b, wkt_b, kv, part);
    // combine z + 1/16 s-mean
    attn_reduce<<<dim3(4), thr, 0, stream>>>(part, out);
}